// Round 1
// 151.767 us; speedup vs baseline: 1.3709x; 1.3709x over previous
//
#include <hip/hip_runtime.h>

// ---------------------------------------------------------------------------
// color_invariant_quadruplet: 3-hop label gather + 6-way equality embedding sum
//
// The 6 equality bits take 64 combinations; each maps to a fixed 64-float row.
// Pipeline:
//   K0 : build 64x64 table (16 KB) with reference add order (bit-exact)
//   K1 : per g-edge packed endpoint labels           (latency-bound, tiny)
//   K2 : per h-edge packed (z_src_src, z_dst_dst)    (latency-bound, tiny)
//   K3a: per i-edge 6-bit combo byte                 (latency-bound, 2 MB out)
//   K3b: pure streaming table-row write              (write-BW-bound, 512 MB)
//
// Round 1 change: split old fused K3 (gather+combo+write, 16x redundant combo
// math and a 3-deep dependent load chain in front of every 16B store) into
// K3a (combo once per edge) + K3b (fill-kernel-shaped streaming write).
// ---------------------------------------------------------------------------

#define N_FEAT 64

// K0: table[combo][f] = e1[b0][f] + e2[b1][f] + ... + e6[b5][f]
// Same left-to-right f32 add order as the reference -> bit-exact.
__global__ void build_table_kernel(const float* __restrict__ e1,
                                   const float* __restrict__ e2,
                                   const float* __restrict__ e3,
                                   const float* __restrict__ e4,
                                   const float* __restrict__ e5,
                                   const float* __restrict__ e6,
                                   float* __restrict__ table) {
    int idx = blockIdx.x * blockDim.x + threadIdx.x;   // 0 .. 4095
    if (idx >= 64 * N_FEAT) return;
    int combo = idx >> 6;
    int f     = idx & (N_FEAT - 1);
    float v = e1[((combo >> 0) & 1) * N_FEAT + f];
    v      += e2[((combo >> 1) & 1) * N_FEAT + f];
    v      += e3[((combo >> 2) & 1) * N_FEAT + f];
    v      += e4[((combo >> 3) & 1) * N_FEAT + f];
    v      += e5[((combo >> 4) & 1) * N_FEAT + f];
    v      += e6[((combo >> 5) & 1) * N_FEAT + f];
    table[idx] = v;
}

// K1: per g-edge packed endpoint labels (z in 0..7 fits uchar)
__global__ void hop1_kernel(const int* __restrict__ z,
                            const int* __restrict__ src_g,
                            const int* __restrict__ dst_g,
                            uchar2* __restrict__ zg,
                            int n) {
    int e = blockIdx.x * blockDim.x + threadIdx.x;
    if (e >= n) return;
    uchar2 p;
    p.x = (unsigned char)z[src_g[e]];
    p.y = (unsigned char)z[dst_g[e]];
    zg[e] = p;
}

// K2: per h-edge packed (z_src_src, z_dst_dst)
__global__ void hop2_kernel(const uchar2* __restrict__ zg,
                            const int* __restrict__ src_h,
                            const int* __restrict__ dst_h,
                            uchar2* __restrict__ zh,
                            int n) {
    int e = blockIdx.x * blockDim.x + threadIdx.x;
    if (e >= n) return;
    uchar2 p;
    p.x = zg[src_h[e]].x;   // z_src[src_h]
    p.y = zg[dst_h[e]].y;   // z_dst[dst_h]
    zh[e] = p;
}

// K3a: one thread per i-edge -> 6-bit combo byte.
// All the random (latency-bound) gathers live here; 2M threads of TLP hide
// the zh L2-hit latency. Output is a coalesced 2 MB byte stream.
__global__ void combo_kernel(const uchar2* __restrict__ zh,
                             const int* __restrict__ src_i,
                             const int* __restrict__ dst_i,
                             unsigned char* __restrict__ combo,
                             int n) {
    int e = blockIdx.x * blockDim.x + threadIdx.x;
    if (e >= n) return;
    uchar2 p = zh[src_i[e]];    // za = p.x, zc = p.y
    uchar2 q = zh[dst_i[e]];    // zb = q.x, zd = q.y
    int za = p.x, zc = p.y, zb = q.x, zd = q.y;
    int cb = (int)(za == zc)
           | ((int)(za == zb) << 1)
           | ((int)(zc == zb) << 2)
           | ((int)(za == zd) << 3)
           | ((int)(zc == zd) << 4)
           | ((int)(zb == zd) << 5);
    combo[e] = (unsigned char)cb;
}

// K3b: pure streaming write. 16 threads per i-edge; each writes one float4
// (each wave stores 1 KB fully-coalesced). Only reads: combo byte (broadcast
// within the 16-lane group) and the table row (16 KB table stays hot in L1).
// This is structurally the fillBuffer kernel -> target ~6.8 TB/s.
__global__ void write_kernel(const unsigned char* __restrict__ combo,
                             const float* __restrict__ table,
                             float* __restrict__ out,
                             int n) {
    long long t = (long long)blockIdx.x * blockDim.x + threadIdx.x;
    int e = (int)(t >> 4);
    int c = (int)(t & 15);
    if (e >= n) return;
    int cb = combo[e];
    const float4* row = (const float4*)(table + cb * N_FEAT);
    float4 v = row[c];
    float4* orow = (float4*)(out + (size_t)e * N_FEAT);
    orow[c] = v;
}

extern "C" void kernel_launch(void* const* d_in, const int* in_sizes, int n_in,
                              void* d_out, int out_size, void* d_ws, size_t ws_size,
                              hipStream_t stream) {
    // setup_inputs order: z, src_g, dst_g, src_h, dst_h, src_i, dst_i, e1..e6
    const int* z     = (const int*)d_in[0];
    const int* src_g = (const int*)d_in[1];
    const int* dst_g = (const int*)d_in[2];
    const int* src_h = (const int*)d_in[3];
    const int* dst_h = (const int*)d_in[4];
    const int* src_i = (const int*)d_in[5];
    const int* dst_i = (const int*)d_in[6];
    const float* e1  = (const float*)d_in[7];
    const float* e2  = (const float*)d_in[8];
    const float* e3  = (const float*)d_in[9];
    const float* e4  = (const float*)d_in[10];
    const float* e5  = (const float*)d_in[11];
    const float* e6  = (const float*)d_in[12];

    const int E_G = in_sizes[1];
    const int E_H = in_sizes[3];
    const int E_I = in_sizes[5];

    // Workspace layout (256B-aligned):
    //   [0, 16384)            : float table[64][64]
    //   [+2*E_G]              : uchar2 zg[E_G]
    //   [+2*E_H]              : uchar2 zh[E_H]
    //   [+E_I]                : uchar combo[E_I]
    char* ws = (char*)d_ws;
    float*  table = (float*)ws;
    size_t  off   = 64 * N_FEAT * sizeof(float);               // 16384
    uchar2* zg    = (uchar2*)(ws + off);
    off += (size_t)E_G * sizeof(uchar2);
    off  = (off + 255) & ~(size_t)255;
    uchar2* zh    = (uchar2*)(ws + off);
    off += (size_t)E_H * sizeof(uchar2);
    off  = (off + 255) & ~(size_t)255;
    unsigned char* combo = (unsigned char*)(ws + off);

    float* out = (float*)d_out;

    // K0: 64*64 = 4096 entries
    build_table_kernel<<<16, 256, 0, stream>>>(e1, e2, e3, e4, e5, e6, table);

    // K1: E_G edges
    hop1_kernel<<<(E_G + 255) / 256, 256, 0, stream>>>(z, src_g, dst_g, zg, E_G);

    // K2: E_H edges
    hop2_kernel<<<(E_H + 255) / 256, 256, 0, stream>>>(zg, src_h, dst_h, zh, E_H);

    // K3a: E_I edges -> combo bytes
    combo_kernel<<<(E_I + 255) / 256, 256, 0, stream>>>(zh, src_i, dst_i, combo, E_I);

    // K3b: E_I edges, 16 threads each -> 512 MB streaming write
    long long total = (long long)E_I * 16;
    int blocks = (int)((total + 255) / 256);
    write_kernel<<<blocks, 256, 0, stream>>>(combo, table, out, E_I);
}